// Round 3
// baseline (533.938 us; speedup 1.0000x reference)
//
#include <hip/hip_runtime.h>
#include <cstdint>
#include <cstddef>

#define D_MODEL 2048
#define NHEAD 16
#define DK 128
#define SEQ 2048
#define BATCH 2
#define NTOK (BATCH * SEQ)  // 4096

typedef __bf16 bf16;
typedef __bf16 bf16x2 __attribute__((ext_vector_type(2)));
typedef __bf16 bf16x4 __attribute__((ext_vector_type(4)));
typedef __bf16 bf16x8 __attribute__((ext_vector_type(8)));
typedef float f32x4 __attribute__((ext_vector_type(4)));

// ---- global -> LDS direct copy (16B per lane). LDS base must be wave-uniform;
// HW writes lane i at lds_base + i*16. ----
__device__ __forceinline__ void g2lds16(const void* g, void* l) {
  __builtin_amdgcn_global_load_lds(
      (const __attribute__((address_space(1))) void*)g,
      (__attribute__((address_space(3))) void*)l, 16, 0, 0);
}

__device__ __forceinline__ void cstore(float* p, float v) { *p = v; }
__device__ __forceinline__ void cstore(bf16* p, float v) { *p = (bf16)v; }

// ---------------- f32 -> bf16 convert (vectorized) ----------------
__global__ void k_f32_to_bf16(const float* __restrict__ in, bf16* __restrict__ out, int n4) {
  int i = blockIdx.x * blockDim.x + threadIdx.x;
  if (i >= n4) return;
  const float4 v = ((const float4*)in)[i];
  bf16x4 o = {(bf16)v.x, (bf16)v.y, (bf16)v.z, (bf16)v.w};
  ((bf16x4*)out)[i] = o;
}

// ---------------- RoPE (interleaved pairs) on Q and K ----------------
__global__ void k_rope(bf16* __restrict__ Q, bf16* __restrict__ K, const int* __restrict__ pos) {
  int id = blockIdx.x * 256 + threadIdx.x;  // pair index within tensor
  bf16* T = blockIdx.y ? K : Q;
  int f = id & 63;
  int h = (id >> 6) & 15;
  int row = id >> 10;  // b*SEQ + s, 0..4095
  float p = (float)pos[row];
  // inv_freq = 10000^(-f/64) = exp2(-f * log2(10000)/64)
  float ang = p * exp2f((float)f * -0.20762050593121503f);
  float s, c;
  __sincosf(ang, &s, &c);
  size_t base = (size_t)row * D_MODEL + h * DK + 2 * f;
  bf16x2 v = *(bf16x2*)&T[base];
  float x1 = (float)v[0], x2 = (float)v[1];
  bf16x2 o = {(bf16)(x1 * c - x2 * s), (bf16)(x1 * s + x2 * c)};
  *(bf16x2*)&T[base] = o;
}

// ---------------- NT GEMM: C[i,n] = sum_k A[i,k] * B[n,k], bf16 in, f32 acc ----
// 128x128 tile, BK=32, 256 threads (4 waves, 2x2), 16x16x32 MFMA, 4x4 frags/wave.
template <typename OutT>
__global__ __launch_bounds__(256, 2) void k_gemm_nt(
    const bf16* __restrict__ A, const bf16* __restrict__ B0, const bf16* __restrict__ B1,
    const bf16* __restrict__ B2, OutT* __restrict__ C0, OutT* __restrict__ C1,
    OutT* __restrict__ C2, int M, int N, int K) {
  const bf16* Bp = B0;
  OutT* Cp = C0;
  if (blockIdx.z == 1) { Bp = B1; Cp = C1; }
  else if (blockIdx.z == 2) { Bp = B2; Cp = C2; }

  __shared__ bf16 As[128 * 32];
  __shared__ bf16 Bs[128 * 32];

  const int t = threadIdx.x;
  const int w = t >> 6;
  const int lane = t & 63;
  const int lr = lane & 15;
  const int lg = lane >> 4;
  const int wr = w >> 1, wc = w & 1;
  const int bm = blockIdx.y, bn = blockIdx.x;

  f32x4 acc[4][4] = {};

  const int srow = lane >> 2;        // row within 16-row chunk
  const int scol = (lane & 3) * 8;   // k-element offset

  const int kt_iters = K >> 5;
  for (int kt = 0; kt < kt_iters; ++kt) {
    const int kbase = kt * 32;
#pragma unroll
    for (int i = 0; i < 2; ++i) {
      int chunk = w * 2 + i;  // 0..7, 16 rows each
      int row = chunk * 16 + srow;
      g2lds16(&A[(size_t)(bm * 128 + row) * K + kbase + scol], &As[chunk * 512]);
      g2lds16(&Bp[(size_t)(bn * 128 + row) * K + kbase + scol], &Bs[chunk * 512]);
    }
    asm volatile("s_waitcnt vmcnt(0)" ::: "memory");
    __syncthreads();

    bf16x8 af[4], bfr[4];
#pragma unroll
    for (int m = 0; m < 4; ++m)
      af[m] = *(const bf16x8*)&As[(wr * 64 + m * 16 + lr) * 32 + lg * 8];
#pragma unroll
    for (int n = 0; n < 4; ++n)
      bfr[n] = *(const bf16x8*)&Bs[(wc * 64 + n * 16 + lr) * 32 + lg * 8];
#pragma unroll
    for (int m = 0; m < 4; ++m)
#pragma unroll
      for (int n = 0; n < 4; ++n)
        acc[m][n] = __builtin_amdgcn_mfma_f32_16x16x32_bf16(af[m], bfr[n], acc[m][n], 0, 0, 0);
    __syncthreads();
  }

#pragma unroll
  for (int m = 0; m < 4; ++m) {
    int rowb = bm * 128 + wr * 64 + m * 16 + lg * 4;
#pragma unroll
    for (int n = 0; n < 4; ++n) {
      int col = bn * 128 + wc * 64 + n * 16 + lr;
#pragma unroll
      for (int r = 0; r < 4; ++r) cstore(&Cp[(size_t)(rowb + r) * N + col], acc[m][n][r]);
    }
  }
}

// ---------------- causal flash attention, bf16 in, f32 softmax state ----------
// block: 64 q-rows of one (b,h); 4 waves x 16 q-rows. k-tiles of 32.
__global__ __launch_bounds__(256, 2) void k_attn(const bf16* __restrict__ Q,
                                                 const bf16* __restrict__ K,
                                                 const bf16* __restrict__ V,
                                                 bf16* __restrict__ O) {
  const int qblk = blockIdx.x;  // 0..31
  const int h = blockIdx.y;
  const int b = blockIdx.z;
  const int t = threadIdx.x;
  const int w = t >> 6, lane = t & 63;
  const int lr = lane & 15, lg = lane >> 4;

  const int qb = qblk * 64;
  const size_t rowbase = (size_t)b * SEQ;
  const int hoff = h * DK;

  __shared__ bf16 VT[128 * 32];   // V^T tile: [d][k]
  __shared__ bf16 Pb[4][16 * 32]; // per-wave P transpose buffer [q][k]

  // Q fragments (A operand): row = lane&15 of this wave's 16 rows
  bf16x8 qf[4];
  {
    size_t qrow = rowbase + qb + w * 16 + lr;
#pragma unroll
    for (int c = 0; c < 4; ++c)
      qf[c] = *(const bf16x8*)&Q[qrow * D_MODEL + hoff + c * 32 + lg * 8];
  }

  f32x4 o[8] = {};
  f32x4 mrow = {-1e30f, -1e30f, -1e30f, -1e30f};
  f32x4 lrow = {};

  const int qmaxw = qb + w * 16 + 15;
  const int ktiles = qb / 32 + 2;
  const float scale = 0.08838834764831845f;  // 1/sqrt(128)

  for (int kt = 0; kt < ktiles; ++kt) {
    const int k0 = kt * 32;
    __syncthreads();  // protect VT from previous iteration's readers
    {
      // stage V^T tile: 256 threads; thread covers 16 d-values of one key row.
      // kk = t>>3 (0..31 key), d0 = (t&7)*16 (0..112). Fully covers 128x32.
      int kk = t >> 3, d0 = (t & 7) * 16;
      const bf16* vp = &V[(rowbase + k0 + kk) * D_MODEL + hoff + d0];
      bf16x8 v0 = *(const bf16x8*)vp;
      bf16x8 v1 = *(const bf16x8*)(vp + 8);
#pragma unroll
      for (int j = 0; j < 8; ++j) {
        VT[(d0 + j) * 32 + kk] = v0[j];
        VT[(d0 + 8 + j) * 32 + kk] = v1[j];
      }
    }
    __syncthreads();

    if (k0 > qmaxw) continue;  // this wave fully masked for this tile

    // scores: two 16-col tiles over 32 keys
    f32x4 sc[2];
#pragma unroll
    for (int tt = 0; tt < 2; ++tt) {
      f32x4 a = {};
      size_t krow = rowbase + k0 + tt * 16 + lr;
#pragma unroll
      for (int c = 0; c < 4; ++c) {
        bf16x8 kf = *(const bf16x8*)&K[krow * D_MODEL + hoff + c * 32 + lg * 8];
        a = __builtin_amdgcn_mfma_f32_16x16x32_bf16(qf[c], kf, a, 0, 0, 0);
      }
      sc[tt] = a * scale;
    }
    // causal mask: row q = qb+w*16+4*lg+r (C layout), col k = k0+tt*16+lr
    const int qrow0 = qb + w * 16 + lg * 4;
#pragma unroll
    for (int tt = 0; tt < 2; ++tt) {
      int kcol = k0 + tt * 16 + lr;
#pragma unroll
      for (int r = 0; r < 4; ++r)
        if (kcol > qrow0 + r) sc[tt][r] = -3.0e38f;
    }
    // row max across 32 cols (cols live across the 16 lanes of each group)
    f32x4 tmax;
#pragma unroll
    for (int r = 0; r < 4; ++r) tmax[r] = fmaxf(sc[0][r], sc[1][r]);
#pragma unroll
    for (int off = 8; off >= 1; off >>= 1)
#pragma unroll
      for (int r = 0; r < 4; ++r) tmax[r] = fmaxf(tmax[r], __shfl_xor(tmax[r], off));

    f32x4 mnew, alpha;
#pragma unroll
    for (int r = 0; r < 4; ++r) {
      mnew[r] = fmaxf(mrow[r], tmax[r]);
      alpha[r] = __expf(mrow[r] - mnew[r]);
    }
    f32x4 psum = {};
#pragma unroll
    for (int tt = 0; tt < 2; ++tt)
#pragma unroll
      for (int r = 0; r < 4; ++r) {
        float p = __expf(sc[tt][r] - mnew[r]);
        sc[tt][r] = p;
        psum[r] += p;
      }
#pragma unroll
    for (int off = 8; off >= 1; off >>= 1)
#pragma unroll
      for (int r = 0; r < 4; ++r) psum[r] += __shfl_xor(psum[r], off);

    // P -> LDS transpose (per-wave buffer), then re-read as MFMA A operand
#pragma unroll
    for (int tt = 0; tt < 2; ++tt)
#pragma unroll
      for (int r = 0; r < 4; ++r)
        Pb[w][(lg * 4 + r) * 32 + tt * 16 + lr] = (bf16)sc[tt][r];
    asm volatile("s_waitcnt lgkmcnt(0)" ::: "memory");
    bf16x8 pf = *(const bf16x8*)&Pb[w][lr * 32 + lg * 8];

#pragma unroll
    for (int r = 0; r < 4; ++r) {
      lrow[r] = lrow[r] * alpha[r] + psum[r];
      mrow[r] = mnew[r];
    }
#pragma unroll
    for (int nt = 0; nt < 8; ++nt) {
#pragma unroll
      for (int r = 0; r < 4; ++r) o[nt][r] *= alpha[r];
      bf16x8 vf = *(const bf16x8*)&VT[(nt * 16 + lr) * 32 + lg * 8];
      o[nt] = __builtin_amdgcn_mfma_f32_16x16x32_bf16(pf, vf, o[nt], 0, 0, 0);
    }
  }

  size_t orow = rowbase + qb + w * 16 + lg * 4;
#pragma unroll
  for (int nt = 0; nt < 8; ++nt)
#pragma unroll
    for (int r = 0; r < 4; ++r)
      O[(orow + r) * D_MODEL + hoff + nt * 16 + lr] = (bf16)(o[nt][r] / lrow[r]);
}

// ---------------- launch ----------------
extern "C" void kernel_launch(void* const* d_in, const int* in_sizes, int n_in, void* d_out,
                              int out_size, void* d_ws, size_t ws_size, hipStream_t stream) {
  const float* x = (const float*)d_in[0];
  const int* pos = (const int*)d_in[1];
  const float* Wq = (const float*)d_in[2];
  const float* Wk = (const float*)d_in[3];
  const float* Wv = (const float*)d_in[4];
  const float* Wo = (const float*)d_in[5];
  float* out = (float*)d_out;

  char* ws = (char*)d_ws;
  const size_t MB = 1u << 20;
  bf16* xb  = (bf16*)(ws);              // 16 MB
  bf16* wqb = (bf16*)(ws + 16 * MB);    // 8 MB
  bf16* wkb = (bf16*)(ws + 24 * MB);
  bf16* wvb = (bf16*)(ws + 32 * MB);
  bf16* wob = (bf16*)(ws + 40 * MB);
  bf16* Qb  = (bf16*)(ws + 48 * MB);    // 16 MB each
  bf16* Kb  = (bf16*)(ws + 64 * MB);
  bf16* Vb  = (bf16*)(ws + 80 * MB);
  bf16* AOb = (bf16*)(ws + 96 * MB);    // ends at 112 MB

  // converts
  {
    int n4 = NTOK * D_MODEL / 4;
    k_f32_to_bf16<<<(n4 + 255) / 256, 256, 0, stream>>>(x, xb, n4);
    int w4 = D_MODEL * D_MODEL / 4;
    k_f32_to_bf16<<<(w4 + 255) / 256, 256, 0, stream>>>(Wq, wqb, w4);
    k_f32_to_bf16<<<(w4 + 255) / 256, 256, 0, stream>>>(Wk, wkb, w4);
    k_f32_to_bf16<<<(w4 + 255) / 256, 256, 0, stream>>>(Wv, wvb, w4);
    k_f32_to_bf16<<<(w4 + 255) / 256, 256, 0, stream>>>(Wo, wob, w4);
  }
  // QKV projections (one launch, z selects weight)
  {
    dim3 g(D_MODEL / 128, NTOK / 128, 3);
    k_gemm_nt<bf16><<<g, 256, 0, stream>>>(xb, wqb, wkb, wvb, Qb, Kb, Vb, NTOK, D_MODEL, D_MODEL);
  }
  // RoPE on Q and K
  {
    int pairs = NTOK * NHEAD * 64;  // per tensor
    k_rope<<<dim3(pairs / 256, 2), 256, 0, stream>>>(Qb, Kb, pos);
  }
  // attention
  k_attn<<<dim3(SEQ / 64, NHEAD, BATCH), 256, 0, stream>>>(Qb, Kb, Vb, AOb);
  // output projection -> f32 d_out
  {
    dim3 g(D_MODEL / 128, NTOK / 128, 1);
    k_gemm_nt<float><<<g, 256, 0, stream>>>(AOb, wob, wob, wob, out, out, out, NTOK, D_MODEL, D_MODEL);
  }
}

// Round 4
// 394.581 us; speedup vs baseline: 1.3532x; 1.3532x over previous
//
#include <hip/hip_runtime.h>
#include <cstdint>
#include <cstddef>

#define D_MODEL 2048
#define NHEAD 16
#define DK 128
#define SEQ 2048
#define BATCH 2
#define NTOK (BATCH * SEQ)  // 4096
#define NQB 32              // 64-row q-tiles per (b,h)

typedef __bf16 bf16;
typedef __bf16 bf16x2 __attribute__((ext_vector_type(2)));
typedef __bf16 bf16x4 __attribute__((ext_vector_type(4)));
typedef __bf16 bf16x8 __attribute__((ext_vector_type(8)));
typedef float f32x4 __attribute__((ext_vector_type(4)));

// ---- global -> LDS direct copy (16B per lane). LDS base must be wave-uniform;
// HW writes lane i at lds_base + i*16. ----
__device__ __forceinline__ void g2lds16(const void* g, void* l) {
  __builtin_amdgcn_global_load_lds(
      (const __attribute__((address_space(1))) void*)g,
      (__attribute__((address_space(3))) void*)l, 16, 0, 0);
}

__device__ __forceinline__ void cstore(float* p, float v) { *p = v; }
__device__ __forceinline__ void cstore(bf16* p, float v) { *p = (bf16)v; }

// ---------------- f32 -> bf16 convert (vectorized) ----------------
__global__ void k_f32_to_bf16(const float* __restrict__ in, bf16* __restrict__ out, int n4) {
  int i = blockIdx.x * blockDim.x + threadIdx.x;
  if (i >= n4) return;
  const float4 v = ((const float4*)in)[i];
  bf16x4 o = {(bf16)v.x, (bf16)v.y, (bf16)v.z, (bf16)v.w};
  ((bf16x4*)out)[i] = o;
}

// ---------------- RoPE (interleaved pairs) on Q and K ----------------
__global__ void k_rope(bf16* __restrict__ Q, bf16* __restrict__ K, const int* __restrict__ pos) {
  int id = blockIdx.x * 256 + threadIdx.x;  // pair index within tensor
  bf16* T = blockIdx.y ? K : Q;
  int f = id & 63;
  int h = (id >> 6) & 15;
  int row = id >> 10;  // b*SEQ + s, 0..4095
  float p = (float)pos[row];
  // inv_freq = 10000^(-f/64) = exp2(-f * log2(10000)/64)
  float ang = p * exp2f((float)f * -0.20762050593121503f);
  float s, c;
  __sincosf(ang, &s, &c);
  size_t base = (size_t)row * D_MODEL + h * DK + 2 * f;
  bf16x2 v = *(bf16x2*)&T[base];
  float x1 = (float)v[0], x2 = (float)v[1];
  bf16x2 o = {(bf16)(x1 * c - x2 * s), (bf16)(x1 * s + x2 * c)};
  *(bf16x2*)&T[base] = o;
}

// ---------------- NT GEMM: C[i,n] = sum_k A[i,k] * B[n,k], bf16 in, f32 acc ----
// 128x128 tile, BK=32, 256 threads (4 waves, 2x2), 16x16x32 MFMA, 4x4 frags/wave.
template <typename OutT>
__global__ __launch_bounds__(256, 2) void k_gemm_nt(
    const bf16* __restrict__ A, const bf16* __restrict__ B0, const bf16* __restrict__ B1,
    const bf16* __restrict__ B2, OutT* __restrict__ C0, OutT* __restrict__ C1,
    OutT* __restrict__ C2, int M, int N, int K) {
  const bf16* Bp = B0;
  OutT* Cp = C0;
  if (blockIdx.z == 1) { Bp = B1; Cp = C1; }
  else if (blockIdx.z == 2) { Bp = B2; Cp = C2; }

  __shared__ bf16 As[128 * 32];
  __shared__ bf16 Bs[128 * 32];

  const int t = threadIdx.x;
  const int w = t >> 6;
  const int lane = t & 63;
  const int lr = lane & 15;
  const int lg = lane >> 4;
  const int wr = w >> 1, wc = w & 1;
  const int bm = blockIdx.y, bn = blockIdx.x;

  f32x4 acc[4][4] = {};

  const int srow = lane >> 2;        // row within 16-row chunk
  const int scol = (lane & 3) * 8;   // k-element offset

  const int kt_iters = K >> 5;
  for (int kt = 0; kt < kt_iters; ++kt) {
    const int kbase = kt * 32;
#pragma unroll
    for (int i = 0; i < 2; ++i) {
      int chunk = w * 2 + i;  // 0..7, 16 rows each
      int row = chunk * 16 + srow;
      g2lds16(&A[(size_t)(bm * 128 + row) * K + kbase + scol], &As[chunk * 512]);
      g2lds16(&Bp[(size_t)(bn * 128 + row) * K + kbase + scol], &Bs[chunk * 512]);
    }
    asm volatile("s_waitcnt vmcnt(0)" ::: "memory");
    __syncthreads();

    bf16x8 af[4], bfr[4];
#pragma unroll
    for (int m = 0; m < 4; ++m)
      af[m] = *(const bf16x8*)&As[(wr * 64 + m * 16 + lr) * 32 + lg * 8];
#pragma unroll
    for (int n = 0; n < 4; ++n)
      bfr[n] = *(const bf16x8*)&Bs[(wc * 64 + n * 16 + lr) * 32 + lg * 8];
#pragma unroll
    for (int m = 0; m < 4; ++m)
#pragma unroll
      for (int n = 0; n < 4; ++n)
        acc[m][n] = __builtin_amdgcn_mfma_f32_16x16x32_bf16(af[m], bfr[n], acc[m][n], 0, 0, 0);
    __syncthreads();
  }

#pragma unroll
  for (int m = 0; m < 4; ++m) {
    int rowb = bm * 128 + wr * 64 + m * 16 + lg * 4;
#pragma unroll
    for (int n = 0; n < 4; ++n) {
      int col = bn * 128 + wc * 64 + n * 16 + lr;
#pragma unroll
      for (int r = 0; r < 4; ++r) cstore(&Cp[(size_t)(rowb + r) * N + col], acc[m][n][r]);
    }
  }
}

// ---------------- causal flash attention, bf16 in, f32 softmax state ----------
// Block handles TWO q-tiles {bid, NQB-1-bid} of one (b,h) for uniform work.
// 4 waves x 16 q-rows each; k-tiles of 64.
// VT: u32[128][32] (bf16x2 over k-pairs), XOR-swizzled col' = col ^ ((d&7)<<2).
// Pb: per-wave [16][64] bf16, XOR-swizzled col' = col ^ ((q&7)<<3).
__global__ __launch_bounds__(256, 2) void k_attn(const bf16* __restrict__ Q,
                                                 const bf16* __restrict__ K,
                                                 const bf16* __restrict__ V,
                                                 bf16* __restrict__ O) {
  const int h = blockIdx.y;
  const int b = blockIdx.z;
  const int t = threadIdx.x;
  const int w = t >> 6, lane = t & 63;
  const int lr = lane & 15, lg = lane >> 4;

  const size_t rowbase = (size_t)b * SEQ;
  const int hoff = h * DK;

  __shared__ uint32_t VTu[128 * 32];     // V^T tile, k-pairs packed, swizzled
  __shared__ bf16 Pb[4][16 * 64];        // per-wave P buffer [q][k], swizzled

  const int kp = t & 31;          // k-pair index for VT staging
  const int d0s = (t >> 5) * 16;  // d-block for VT staging

  const float scale = 0.08838834764831845f;  // 1/sqrt(128)

  for (int qsel = 0; qsel < 2; ++qsel) {
    const int qblk = qsel ? (NQB - 1 - (int)blockIdx.x) : (int)blockIdx.x;
    const int qb = qblk * 64;

    // Q fragments (A operand): row = lane&15 of this wave's 16 rows
    bf16x8 qf[4];
    {
      size_t qrow = rowbase + qb + w * 16 + lr;
#pragma unroll
      for (int c = 0; c < 4; ++c)
        qf[c] = *(const bf16x8*)&Q[qrow * D_MODEL + hoff + c * 32 + lg * 8];
    }

    f32x4 o[8] = {};
    f32x4 mrow = {-1e30f, -1e30f, -1e30f, -1e30f};
    f32x4 lrow = {};

    const int ktiles = qblk + 1;  // 64-key tiles; last includes the diagonal

    for (int kt = 0; kt < ktiles; ++kt) {
      const int k0 = kt * 64;
      __syncthreads();  // protect VT from previous iteration's readers
      {
        // stage V^T: thread covers keys {2kp, 2kp+1} x d in [d0s, d0s+16)
        const bf16* vp0 = &V[(rowbase + k0 + 2 * kp) * D_MODEL + hoff + d0s];
        const bf16* vp1 = vp0 + D_MODEL;
        bf16x8 a0 = *(const bf16x8*)vp0;
        bf16x8 a1 = *(const bf16x8*)(vp0 + 8);
        bf16x8 b0 = *(const bf16x8*)vp1;
        bf16x8 b1 = *(const bf16x8*)(vp1 + 8);
#pragma unroll
        for (int j = 0; j < 8; ++j) {
          int d = d0s + j;
          bf16x2 pr = {a0[j], b0[j]};
          VTu[d * 32 + (kp ^ ((d & 7) << 2))] = *(const uint32_t*)&pr;
        }
#pragma unroll
        for (int j = 0; j < 8; ++j) {
          int d = d0s + 8 + j;
          bf16x2 pr = {a1[j], b1[j]};
          VTu[d * 32 + (kp ^ ((d & 7) << 2))] = *(const uint32_t*)&pr;
        }
      }
      __syncthreads();

      // scores: four 16-col tiles over 64 keys
      f32x4 sc[4];
#pragma unroll
      for (int tt = 0; tt < 4; ++tt) {
        f32x4 a = {};
        size_t krow = rowbase + k0 + tt * 16 + lr;
#pragma unroll
        for (int c = 0; c < 4; ++c) {
          bf16x8 kf = *(const bf16x8*)&K[krow * D_MODEL + hoff + c * 32 + lg * 8];
          a = __builtin_amdgcn_mfma_f32_16x16x32_bf16(qf[c], kf, a, 0, 0, 0);
        }
        sc[tt] = a * scale;
      }
      // causal mask: row q = qb+w*16+4*lg+r (C layout), col k = k0+tt*16+lr
      const int qrow0 = qb + w * 16 + lg * 4;
#pragma unroll
      for (int tt = 0; tt < 4; ++tt) {
        int kcol = k0 + tt * 16 + lr;
#pragma unroll
        for (int r = 0; r < 4; ++r)
          if (kcol > qrow0 + r) sc[tt][r] = -3.0e38f;
      }
      // row max across 64 cols (16 lanes x 4 tt)
      f32x4 tmax;
#pragma unroll
      for (int r = 0; r < 4; ++r)
        tmax[r] = fmaxf(fmaxf(sc[0][r], sc[1][r]), fmaxf(sc[2][r], sc[3][r]));
#pragma unroll
      for (int off = 8; off >= 1; off >>= 1)
#pragma unroll
        for (int r = 0; r < 4; ++r) tmax[r] = fmaxf(tmax[r], __shfl_xor(tmax[r], off));

      f32x4 mnew, alpha;
#pragma unroll
      for (int r = 0; r < 4; ++r) {
        mnew[r] = fmaxf(mrow[r], tmax[r]);
        alpha[r] = __expf(mrow[r] - mnew[r]);
      }
      f32x4 psum = {};
#pragma unroll
      for (int tt = 0; tt < 4; ++tt)
#pragma unroll
        for (int r = 0; r < 4; ++r) {
          float p = __expf(sc[tt][r] - mnew[r]);
          sc[tt][r] = p;
          psum[r] += p;
        }
#pragma unroll
      for (int off = 8; off >= 1; off >>= 1)
#pragma unroll
        for (int r = 0; r < 4; ++r) psum[r] += __shfl_xor(psum[r], off);

      // P -> per-wave LDS (swizzled), then re-read as MFMA A operand
#pragma unroll
      for (int tt = 0; tt < 4; ++tt)
#pragma unroll
        for (int r = 0; r < 4; ++r) {
          int q = lg * 4 + r;
          int col = tt * 16 + lr;
          Pb[w][q * 64 + (col ^ ((q & 7) << 3))] = (bf16)sc[tt][r];
        }
      asm volatile("s_waitcnt lgkmcnt(0)" ::: "memory");
      bf16x8 pf0 = *(const bf16x8*)&Pb[w][lr * 64 + ((lg * 8) ^ ((lr & 7) << 3))];
      bf16x8 pf1 = *(const bf16x8*)&Pb[w][lr * 64 + ((32 + lg * 8) ^ ((lr & 7) << 3))];

#pragma unroll
      for (int r = 0; r < 4; ++r) {
        lrow[r] = lrow[r] * alpha[r] + psum[r];
        mrow[r] = mnew[r];
      }
#pragma unroll
      for (int nt = 0; nt < 8; ++nt) {
#pragma unroll
        for (int r = 0; r < 4; ++r) o[nt][r] *= alpha[r];
        int d = nt * 16 + lr;
        bf16x8 vf0 = *(const bf16x8*)&VTu[d * 32 + ((lg * 4) ^ ((d & 7) << 2))];
        bf16x8 vf1 = *(const bf16x8*)&VTu[d * 32 + ((16 + lg * 4) ^ ((d & 7) << 2))];
        o[nt] = __builtin_amdgcn_mfma_f32_16x16x32_bf16(pf0, vf0, o[nt], 0, 0, 0);
        o[nt] = __builtin_amdgcn_mfma_f32_16x16x32_bf16(pf1, vf1, o[nt], 0, 0, 0);
      }
    }

    size_t orow = rowbase + qb + w * 16 + lg * 4;
#pragma unroll
    for (int nt = 0; nt < 8; ++nt)
#pragma unroll
      for (int r = 0; r < 4; ++r)
        O[(orow + r) * D_MODEL + hoff + nt * 16 + lr] = (bf16)(o[nt][r] / lrow[r]);
  }
}

// ---------------- launch ----------------
extern "C" void kernel_launch(void* const* d_in, const int* in_sizes, int n_in, void* d_out,
                              int out_size, void* d_ws, size_t ws_size, hipStream_t stream) {
  const float* x = (const float*)d_in[0];
  const int* pos = (const int*)d_in[1];
  const float* Wq = (const float*)d_in[2];
  const float* Wk = (const float*)d_in[3];
  const float* Wv = (const float*)d_in[4];
  const float* Wo = (const float*)d_in[5];
  float* out = (float*)d_out;

  char* ws = (char*)d_ws;
  const size_t MB = 1u << 20;
  bf16* xb  = (bf16*)(ws);              // 16 MB
  bf16* wqb = (bf16*)(ws + 16 * MB);    // 8 MB
  bf16* wkb = (bf16*)(ws + 24 * MB);
  bf16* wvb = (bf16*)(ws + 32 * MB);
  bf16* wob = (bf16*)(ws + 40 * MB);
  bf16* Qb  = (bf16*)(ws + 48 * MB);    // 16 MB each
  bf16* Kb  = (bf16*)(ws + 64 * MB);
  bf16* Vb  = (bf16*)(ws + 80 * MB);
  bf16* AOb = (bf16*)(ws + 96 * MB);    // ends at 112 MB

  // converts
  {
    int n4 = NTOK * D_MODEL / 4;
    k_f32_to_bf16<<<(n4 + 255) / 256, 256, 0, stream>>>(x, xb, n4);
    int w4 = D_MODEL * D_MODEL / 4;
    k_f32_to_bf16<<<(w4 + 255) / 256, 256, 0, stream>>>(Wq, wqb, w4);
    k_f32_to_bf16<<<(w4 + 255) / 256, 256, 0, stream>>>(Wk, wkb, w4);
    k_f32_to_bf16<<<(w4 + 255) / 256, 256, 0, stream>>>(Wv, wvb, w4);
    k_f32_to_bf16<<<(w4 + 255) / 256, 256, 0, stream>>>(Wo, wob, w4);
  }
  // QKV projections (one launch, z selects weight)
  {
    dim3 g(D_MODEL / 128, NTOK / 128, 3);
    k_gemm_nt<bf16><<<g, 256, 0, stream>>>(xb, wqb, wkb, wvb, Qb, Kb, Vb, NTOK, D_MODEL, D_MODEL);
  }
  // RoPE on Q and K
  {
    int pairs = NTOK * NHEAD * 64;  // per tensor
    k_rope<<<dim3(pairs / 256, 2), 256, 0, stream>>>(Qb, Kb, pos);
  }
  // attention: 16 paired q-tile blocks per (b,h)
  k_attn<<<dim3(NQB / 2, NHEAD, BATCH), 256, 0, stream>>>(Qb, Kb, Vb, AOb);
  // output projection -> f32 d_out
  {
    dim3 g(D_MODEL / 128, NTOK / 128, 1);
    k_gemm_nt<float><<<g, 256, 0, stream>>>(AOb, wob, wob, wob, out, out, out, NTOK, D_MODEL, D_MODEL);
  }
}